// Round 3
// baseline (285.032 us; speedup 1.0000x reference)
//
#include <hip/hip_runtime.h>

#define D_IN 33600
#define N1 1000
#define N2 4605
#define G1_CHUNKS 512    // balanced: block b covers rows [(b*33600)>>9, ((b+1)*33600)>>9)
#define NSCAL 307        // needed x2 scalars: index 15k+1, k=0..306
#define PS_STRIDE 320    // psum row stride (307 padded)
#define RS_BLOCKS 250    // k_reduce_scalars: 4 x1-cols per block
#define SEG1_BLOCKS 161  // ceil(5121/32) col tiles, full j range per block

// K1: partial GEMV1. Block = balanced row chunk; thread t handles 4 cols (float4).
// Streams Wd1 (134.4 MB) once, coalesced 16B/lane -> HBM-bound (~22 us).
// NOTE (prev session R3/R4/R6): do NOT fold later phases into this dispatch.
// grid.sync (+127us), per-block scalar recompute (+26us), transpose rider
// (+20us) all regressed. Plain stream-ordered small dispatches win here.
// Epilogue writes ws1 TRANSPOSED (ws1_T[col][chunk]) so the fused
// reduce+scalars kernel gets coalesced per-wave column reads. Block->chunk
// swizzle keeps the 16 chunks sharing a 64B ws1_T line on one XCD.
__global__ __launch_bounds__(256) void k_gemv1_partial(
    const float* __restrict__ x, const float* __restrict__ Wd1, float* __restrict__ ws1) {
  const int chunk = (blockIdx.x & 7) * 64 + (blockIdx.x >> 3);  // bijective 0..511
  const int t = threadIdx.x;
  if (t >= 250) return;  // 250 * 4 = 1000 cols
  const int r0 = (chunk * D_IN) >> 9;
  const int r1 = ((chunk + 1) * D_IN) >> 9;
  const float* wp = Wd1 + (size_t)r0 * N1 + 4 * t;
  float ax = 0.f, ay = 0.f, az = 0.f, aw = 0.f;
#pragma unroll 8
  for (int i = 0; i < r1 - r0; ++i) {
    float4 w = *(const float4*)(wp + (size_t)i * N1);
    float xv = x[r0 + i];
    ax = fmaf(xv, w.x, ax);
    ay = fmaf(xv, w.y, ay);
    az = fmaf(xv, w.z, az);
    aw = fmaf(xv, w.w, aw);
  }
  // transposed: ws1_T[col * 512 + chunk]
  const int c = 4 * t;
  ws1[(size_t)(c + 0) * G1_CHUNKS + chunk] = ax;
  ws1[(size_t)(c + 1) * G1_CHUNKS + chunk] = ay;
  ws1[(size_t)(c + 2) * G1_CHUNKS + chunk] = az;
  ws1[(size_t)(c + 3) * G1_CHUNKS + chunk] = aw;
}

// K2 (fused R7): 250 blocks, 4 x1-cols each.
// Phase 1: wave w reduces col 4b+w over 512 chunks (coalesced reads of ws1_T
//          + shfl tree) -> x1 value in LDS. x1 never hits global.
// Phase 2: psum[b][k] = sum_{col} x1[col] * Wd2[(4b+col)*N2 + 15k+1].
//          ~18.4 MB of Wd2 line fetches (mandatory: one 4B value per 64B
//          line), spread over 250 blocks; writes coalesced.
__global__ __launch_bounds__(256) void k_reduce_scalars(
    const float* __restrict__ ws1, const float* __restrict__ bd1,
    const float* __restrict__ Wd2, float* __restrict__ psum) {
  const int b = blockIdx.x;       // cols 4b .. 4b+3
  const int t = threadIdx.x;
  const int w = t >> 6;           // wave -> col
  const int g = t & 63;           // lane
  const int c = 4 * b + w;

  __shared__ float x1s[4];
  {
    const float* p = ws1 + (size_t)c * G1_CHUNKS;
    float s = 0.f;
#pragma unroll
    for (int i = 0; i < G1_CHUNKS / 64; ++i) s += p[g + 64 * i];
#pragma unroll
    for (int off = 32; off > 0; off >>= 1) s += __shfl_down(s, off, 64);
    if (g == 0) x1s[w] = fmaxf(s + bd1[c], 0.f);
  }
  __syncthreads();

  const float v0 = x1s[0], v1 = x1s[1], v2 = x1s[2], v3 = x1s[3];
  const float* base = Wd2 + (size_t)(4 * b) * N2;
  for (int k = t; k < NSCAL; k += 256) {
    const float* p = base + 15 * k + 1;
    float sv = v0 * p[0];
    sv = fmaf(v1, p[N2], sv);
    sv = fmaf(v2, p[2 * (size_t)N2], sv);
    sv = fmaf(v3, p[3 * (size_t)N2], sv);
    psum[(size_t)b * PS_STRIDE + k] = sv;  // coalesced across t
  }
}

// K3 (R8): all 4 segments, seg1 now DIRECT (no ws3 round-trip, no finalize
// kernel). 204 blocks:
//   [0,161)   seg1: 32-col tile, FULL j=500 range, 8 j-slices/block reduced
//             in LDS -> out (bias+relu) directly. W1b read exactly once.
//   [161,165) seg2: 2 groups x 2 tiles -> out
//   [165,197) seg3: 16 groups x 2 tiles -> out
//   [197,204) seg4: 1 group (3 scalars) x 7 tiles -> out
// Preamble per block: reconstruct its scalars from the 250 psum partials
// (~16 KB coalesced) + bias + relu.
__global__ __launch_bounds__(256) void k_segments(
    const float* __restrict__ psum, const float* __restrict__ bd2,
    const float* __restrict__ W1a, const float* __restrict__ b1a,
    const float* __restrict__ W1b, const float* __restrict__ b1b,
    const float* __restrict__ W2a, const float* __restrict__ b2a,
    const float* __restrict__ W2b, const float* __restrict__ b2b,
    const float* __restrict__ W3a, const float* __restrict__ b3a,
    const float* __restrict__ W3b, const float* __restrict__ b3b,
    const float* __restrict__ W4a, const float* __restrict__ b4a,
    const float* __restrict__ W4b, const float* __restrict__ b4b,
    float* __restrict__ out) {
  __shared__ float sHs[16];
  __shared__ float sH[500 * 16];     // seg1 uses all 500 rows; others first 100
  __shared__ float pred[16][17];
  __shared__ float red[256 * 17];    // seg1 slice-reduce, pad-17 (conflict-free)
  const int b = blockIdx.x;
  const int t = threadIdx.x;

  if (b < SEG1_BLOCKS) {
    // ---------------- seg1 direct ----------------
    const int colbase = b * 32;
    const int c = t & 31;
    const int slice = t >> 5;        // 0..7, j = slice, slice+8, ...
    // preamble: sHs[0..15] from psum (k0 = 0)
    {
      const int kl = t >> 4, pc = t & 15;
      float s = 0.f;
#pragma unroll 4
      for (int i = pc; i < RS_BLOCKS; i += 16) s += psum[(size_t)i * PS_STRIDE + kl];
      pred[kl][pc] = s;
      __syncthreads();
      if (t < 16) {
        float sum = 0.f;
#pragma unroll
        for (int i = 0; i < 16; ++i) sum += pred[t][i];
        sHs[t] = fmaxf(sum + bd2[15 * t + 1], 0.f);
      }
      __syncthreads();
    }
    // h table: 500 x 16 (32 KB LDS)
    for (int e = t; e < 500 * 16; e += 256) {
      const int j = e >> 4, k = e & 15;
      sH[e] = fmaxf(fmaf(sHs[k], W1a[j], b1a[j]), 0.f);
    }
    __syncthreads();

    const int m = colbase + c;
    const int mc = (m < 5121) ? m : 5120;  // clamp (uniform flow for syncs)
    float acc[16];
#pragma unroll
    for (int k = 0; k < 16; ++k) acc[k] = 0.f;
    const float* wb = W1b + mc;
#pragma unroll 2
    for (int j = slice; j < 500; j += 8) {
      const float w = wb[(size_t)j * 5121];            // 128B segment per slice
      const float4* hp = (const float4*)(sH + j * 16); // broadcast within slice
      const float4 h0 = hp[0], h1 = hp[1], h2 = hp[2], h3 = hp[3];
      acc[0]  = fmaf(h0.x, w, acc[0]);   acc[1]  = fmaf(h0.y, w, acc[1]);
      acc[2]  = fmaf(h0.z, w, acc[2]);   acc[3]  = fmaf(h0.w, w, acc[3]);
      acc[4]  = fmaf(h1.x, w, acc[4]);   acc[5]  = fmaf(h1.y, w, acc[5]);
      acc[6]  = fmaf(h1.z, w, acc[6]);   acc[7]  = fmaf(h1.w, w, acc[7]);
      acc[8]  = fmaf(h2.x, w, acc[8]);   acc[9]  = fmaf(h2.y, w, acc[9]);
      acc[10] = fmaf(h2.z, w, acc[10]);  acc[11] = fmaf(h2.w, w, acc[11]);
      acc[12] = fmaf(h3.x, w, acc[12]);  acc[13] = fmaf(h3.y, w, acc[13]);
      acc[14] = fmaf(h3.z, w, acc[14]);  acc[15] = fmaf(h3.w, w, acc[15]);
    }
    // slice reduce: red[t][k], stride 17 -> conflict-free b32
#pragma unroll
    for (int k = 0; k < 16; ++k) red[t * 17 + k] = acc[k];
    __syncthreads();
    {
      const int c2 = t & 31, kq = t >> 5;  // kq 0..7 -> k = 2kq, 2kq+1
      const int m2 = colbase + c2;
      if (m2 < 5121) {
        const float bv0 = b1b[m2];
#pragma unroll
        for (int q = 0; q < 2; ++q) {
          const int k = kq * 2 + q;
          float s = 0.f;
#pragma unroll
          for (int sl = 0; sl < 8; ++sl) s += red[(sl * 32 + c2) * 17 + k];
          out[(size_t)k * 5121 + m2] = fmaxf(s + bv0, 0.f);
        }
      }
    }
    return;
  }

  // ---------------- seg2/3/4 generic ----------------
  const int br = b - SEG1_BLOCKS;
  const float *Wa, *ba, *Wb, *bb;
  int outn, colbase, jcount, k0, kn;
  float* dst;
  int dst_stride;

  if (br < 4) {
    const int g = br >> 1, tile = br & 1;
    Wa = W2a; ba = b2a; Wb = W2b; bb = b2b;
    outn = 257; colbase = tile * 256; jcount = 100;
    k0 = 16 + g * 16; kn = 16;
    dst = out + 81936 + (size_t)g * 16 * 257; dst_stride = 257;
  } else if (br < 36) {
    const int r = br - 4, g = r >> 1, tile = r & 1;
    Wa = W3a; ba = b3a; Wb = W3b; bb = b3b;
    outn = 321; colbase = tile * 256; jcount = 100;
    k0 = 48 + g * 16; kn = 16;
    dst = out + 90160 + (size_t)g * 16 * 321; dst_stride = 321;
  } else {
    const int tile = br - 36;
    Wa = W4a; ba = b4a; Wb = W4b; bb = b4b;
    outn = 1542; colbase = tile * 256; jcount = 100;
    k0 = 304; kn = 3;
    dst = out + 172336; dst_stride = 1542;
  }

  // preamble: sS[k0..k0+kn)
  {
    const int kl = t >> 4, pc = t & 15;
    float s = 0.f;
    if (kl < kn) {
      const int kk = k0 + kl;
#pragma unroll 4
      for (int i = pc; i < RS_BLOCKS; i += 16) s += psum[(size_t)i * PS_STRIDE + kk];
    }
    pred[kl][pc] = s;
    __syncthreads();
    if (t < 16) {
      float sum = 0.f;
#pragma unroll
      for (int i = 0; i < 16; ++i) sum += pred[t][i];
      sHs[t] = (t < kn) ? fmaxf(sum + bd2[15 * (k0 + t) + 1], 0.f) : 0.f;
    }
    __syncthreads();
  }

  for (int e = t; e < jcount * 16; e += 256) {
    const int j = e >> 4, k = e & 15;
    float hv = 0.f;
    if (k < kn) hv = fmaxf(fmaf(sHs[k], Wa[j], ba[j]), 0.f);
    sH[e] = hv;  // layout: sH[j*16 + k]
  }
  __syncthreads();

  const int m = colbase + t;
  if (m < outn) {
    float acc[16];
#pragma unroll
    for (int k = 0; k < 16; ++k) acc[k] = 0.f;
    const float* wb = Wb + m;
    // depth-2 pipelined: both weight loads issue before the FMA chains.
    for (int j = 0; j < jcount; j += 2) {
      const float w0 = wb[(size_t)j * outn];            // coalesced across lanes
      const float w1 = wb[(size_t)(j + 1) * outn];
      const float4* hp0 = (const float4*)(sH + j * 16); // broadcast reads
      const float4 a0 = hp0[0], a1 = hp0[1], a2 = hp0[2], a3 = hp0[3];
      acc[0]  = fmaf(a0.x, w0, acc[0]);   acc[1]  = fmaf(a0.y, w0, acc[1]);
      acc[2]  = fmaf(a0.z, w0, acc[2]);   acc[3]  = fmaf(a0.w, w0, acc[3]);
      acc[4]  = fmaf(a1.x, w0, acc[4]);   acc[5]  = fmaf(a1.y, w0, acc[5]);
      acc[6]  = fmaf(a1.z, w0, acc[6]);   acc[7]  = fmaf(a1.w, w0, acc[7]);
      acc[8]  = fmaf(a2.x, w0, acc[8]);   acc[9]  = fmaf(a2.y, w0, acc[9]);
      acc[10] = fmaf(a2.z, w0, acc[10]);  acc[11] = fmaf(a2.w, w0, acc[11]);
      acc[12] = fmaf(a3.x, w0, acc[12]);  acc[13] = fmaf(a3.y, w0, acc[13]);
      acc[14] = fmaf(a3.z, w0, acc[14]);  acc[15] = fmaf(a3.w, w0, acc[15]);
      const float4* hp1 = (const float4*)(sH + (j + 1) * 16);
      const float4 c0 = hp1[0], c1 = hp1[1], c2 = hp1[2], c3 = hp1[3];
      acc[0]  = fmaf(c0.x, w1, acc[0]);   acc[1]  = fmaf(c0.y, w1, acc[1]);
      acc[2]  = fmaf(c0.z, w1, acc[2]);   acc[3]  = fmaf(c0.w, w1, acc[3]);
      acc[4]  = fmaf(c1.x, w1, acc[4]);   acc[5]  = fmaf(c1.y, w1, acc[5]);
      acc[6]  = fmaf(c1.z, w1, acc[6]);   acc[7]  = fmaf(c1.w, w1, acc[7]);
      acc[8]  = fmaf(c2.x, w1, acc[8]);   acc[9]  = fmaf(c2.y, w1, acc[9]);
      acc[10] = fmaf(c2.z, w1, acc[10]);  acc[11] = fmaf(c2.w, w1, acc[11]);
      acc[12] = fmaf(c3.x, w1, acc[12]);  acc[13] = fmaf(c3.y, w1, acc[13]);
      acc[14] = fmaf(c3.z, w1, acc[14]);  acc[15] = fmaf(c3.w, w1, acc[15]);
    }
    const float bv = bb[m];
    for (int k = 0; k < kn; ++k)
      dst[(size_t)k * dst_stride + m] = fmaxf(acc[k] + bv, 0.f);
  }
}

extern "C" void kernel_launch(void* const* d_in, const int* in_sizes, int n_in,
                              void* d_out, int out_size, void* d_ws, size_t ws_size,
                              hipStream_t stream) {
  const float* x   = (const float*)d_in[0];
  const float* Wd1 = (const float*)d_in[1];
  const float* bd1 = (const float*)d_in[2];
  const float* Wd2 = (const float*)d_in[3];
  const float* bd2 = (const float*)d_in[4];
  const float* W1a = (const float*)d_in[5];
  const float* b1a = (const float*)d_in[6];
  const float* W1b = (const float*)d_in[7];
  const float* b1b = (const float*)d_in[8];
  const float* W2a = (const float*)d_in[9];
  const float* b2a = (const float*)d_in[10];
  const float* W2b = (const float*)d_in[11];
  const float* b2b = (const float*)d_in[12];
  const float* W3a = (const float*)d_in[13];
  const float* b3a = (const float*)d_in[14];
  const float* W3b = (const float*)d_in[15];
  const float* b3b = (const float*)d_in[16];
  const float* W4a = (const float*)d_in[17];
  const float* b4a = (const float*)d_in[18];
  const float* W4b = (const float*)d_in[19];
  const float* b4b = (const float*)d_in[20];
  float* out = (float*)d_out;

  float* ws   = (float*)d_ws;
  float* ws1  = ws;                              // ws1_T: 1000 * 512 floats
  float* psum = ws1 + (size_t)N1 * G1_CHUNKS;    // 250 * 320

  hipLaunchKernelGGL(k_gemv1_partial, dim3(G1_CHUNKS), dim3(256), 0, stream, x, Wd1, ws1);
  hipLaunchKernelGGL(k_reduce_scalars, dim3(RS_BLOCKS), dim3(256), 0, stream,
                     ws1, bd1, Wd2, psum);
  hipLaunchKernelGGL(k_segments, dim3(SEG1_BLOCKS + 43), dim3(256), 0, stream,
                     psum, bd2, W1a, b1a, W1b, b1b, W2a, b2a, W2b, b2b,
                     W3a, b3a, W3b, b3b, W4a, b4a, W4b, b4b, out);
}

// Round 4
// 276.662 us; speedup vs baseline: 1.0303x; 1.0303x over previous
//
#include <hip/hip_runtime.h>

#define D_IN 33600
#define N1 1000
#define N2 4605
#define G1_CHUNKS 512    // balanced: block b covers rows [(b*33600)>>9, ((b+1)*33600)>>9)
#define NSCAL 307        // needed x2 scalars: index 15k+1, k=0..306
#define PS_STRIDE 320    // psum row stride (307 padded)
#define RS_BLOCKS 250    // k_reduce_scalars: 4 x1-cols per block
#define SEG1_JC 10       // seg1 j-chunks of 50 rows each

// R9: clean revert to the R7 structure (best measured 278.2 us).
// R8 post-mortem: seg1-direct (161 thin blocks, full-j, LDS slice-reduce)
// regressed +7 us — the 8000-entry serial h-table fill + 128B/quarter-wave
// strided W1b loads + extra reduce barriers cost more than the saved
// dispatch + 6.6 MB L2-resident ws3 round-trip (~3 us). Wide shallow
// dispatches beat deep fused ones for these small phases on this chip
// (consistent with prior-session R3/R4/R6).

// K1: partial GEMV1. Block = balanced row chunk; thread t handles 4 cols (float4).
// Streams Wd1 (134.4 MB) once, coalesced 16B/lane -> HBM-bound (~22 us).
// Epilogue writes ws1 TRANSPOSED (ws1_T[col][chunk]) so the fused
// reduce+scalars kernel gets coalesced per-wave column reads. Block->chunk
// swizzle keeps the 16 chunks sharing a 64B ws1_T line on one XCD.
__global__ __launch_bounds__(256) void k_gemv1_partial(
    const float* __restrict__ x, const float* __restrict__ Wd1, float* __restrict__ ws1) {
  const int chunk = (blockIdx.x & 7) * 64 + (blockIdx.x >> 3);  // bijective 0..511
  const int t = threadIdx.x;
  if (t >= 250) return;  // 250 * 4 = 1000 cols
  const int r0 = (chunk * D_IN) >> 9;
  const int r1 = ((chunk + 1) * D_IN) >> 9;
  const float* wp = Wd1 + (size_t)r0 * N1 + 4 * t;
  float ax = 0.f, ay = 0.f, az = 0.f, aw = 0.f;
#pragma unroll 8
  for (int i = 0; i < r1 - r0; ++i) {
    float4 w = *(const float4*)(wp + (size_t)i * N1);
    float xv = x[r0 + i];
    ax = fmaf(xv, w.x, ax);
    ay = fmaf(xv, w.y, ay);
    az = fmaf(xv, w.z, az);
    aw = fmaf(xv, w.w, aw);
  }
  // transposed: ws1_T[col * 512 + chunk]
  const int c = 4 * t;
  ws1[(size_t)(c + 0) * G1_CHUNKS + chunk] = ax;
  ws1[(size_t)(c + 1) * G1_CHUNKS + chunk] = ay;
  ws1[(size_t)(c + 2) * G1_CHUNKS + chunk] = az;
  ws1[(size_t)(c + 3) * G1_CHUNKS + chunk] = aw;
}

// K2 (fused): 250 blocks, 4 x1-cols each.
// Phase 1: wave w reduces col 4b+w over 512 chunks (coalesced reads of ws1_T
//          + shfl tree) -> x1 value in LDS. x1 never hits global.
// Phase 2: psum[b][k] = sum_{col} x1[col] * Wd2[(4b+col)*N2 + 15k+1].
//          ~18.4 MB of Wd2 line fetches (mandatory: one 4B value per 64B
//          line), spread over 250 blocks; writes coalesced.
__global__ __launch_bounds__(256) void k_reduce_scalars(
    const float* __restrict__ ws1, const float* __restrict__ bd1,
    const float* __restrict__ Wd2, float* __restrict__ psum) {
  const int b = blockIdx.x;       // cols 4b .. 4b+3
  const int t = threadIdx.x;
  const int w = t >> 6;           // wave -> col
  const int g = t & 63;           // lane
  const int c = 4 * b + w;

  __shared__ float x1s[4];
  {
    const float* p = ws1 + (size_t)c * G1_CHUNKS;
    float s = 0.f;
#pragma unroll
    for (int i = 0; i < G1_CHUNKS / 64; ++i) s += p[g + 64 * i];
#pragma unroll
    for (int off = 32; off > 0; off >>= 1) s += __shfl_down(s, off, 64);
    if (g == 0) x1s[w] = fmaxf(s + bd1[c], 0.f);
  }
  __syncthreads();

  const float v0 = x1s[0], v1 = x1s[1], v2 = x1s[2], v3 = x1s[3];
  const float* base = Wd2 + (size_t)(4 * b) * N2;
  for (int k = t; k < NSCAL; k += 256) {
    const float* p = base + 15 * k + 1;
    float sv = v0 * p[0];
    sv = fmaf(v1, p[N2], sv);
    sv = fmaf(v2, p[2 * (size_t)N2], sv);
    sv = fmaf(v3, p[3 * (size_t)N2], sv);
    psum[(size_t)b * PS_STRIDE + k] = sv;  // coalesced across t
  }
}

// K3: all 4 hypernet segments. Each block: 16-scalar group, j-chunk, <=256 out-cols.
// Preamble: reconstruct this block's 16 scalars from the 250 psum partials
// (coalesced-ish, ~16 KB/block) + bias + relu.
// h-table (jcount x 16) in LDS; 16 acc/thread. j-loop depth-2 pipelined.
// Block roles (253 total):
//   [0,210)   seg1: 21 col tiles x 10 j-chunks(50) -> raw partials to ws3
//   [210,214) seg2: 2 groups x 2 tiles             -> out (bias+relu)
//   [214,246) seg3: 16 groups x 2 tiles            -> out
//   [246,253) seg4: 1 group (3 scalars) x 7 tiles  -> out
__global__ __launch_bounds__(256) void k_segments(
    const float* __restrict__ psum, const float* __restrict__ bd2,
    const float* __restrict__ W1a, const float* __restrict__ b1a, const float* __restrict__ W1b,
    const float* __restrict__ W2a, const float* __restrict__ b2a,
    const float* __restrict__ W2b, const float* __restrict__ b2b,
    const float* __restrict__ W3a, const float* __restrict__ b3a,
    const float* __restrict__ W3b, const float* __restrict__ b3b,
    const float* __restrict__ W4a, const float* __restrict__ b4a,
    const float* __restrict__ W4b, const float* __restrict__ b4b,
    float* __restrict__ ws3, float* __restrict__ out) {
  __shared__ float sHs[16];
  __shared__ float sH[100 * 16];
  __shared__ float pred[16][17];
  const int b = blockIdx.x;
  const int t = threadIdx.x;

  const float *Wa, *ba, *Wb, *bb = nullptr;
  int outn, colbase, jbase = 0, jcount, k0, kn;
  float* dst;
  int dst_stride;
  bool raw;

  if (b < 210) {
    const int tile = b % 21, chunk = b / 21;
    Wa = W1a; ba = b1a; Wb = W1b;
    outn = 5121; colbase = tile * 256; jbase = chunk * 50; jcount = 50;
    k0 = 0; kn = 16;
    dst = ws3 + (size_t)chunk * 16 * 5121; dst_stride = 5121; raw = true;
  } else if (b < 214) {
    const int r = b - 210, g = r >> 1, tile = r & 1;
    Wa = W2a; ba = b2a; Wb = W2b; bb = b2b;
    outn = 257; colbase = tile * 256; jcount = 100;
    k0 = 16 + g * 16; kn = 16;
    dst = out + 81936 + (size_t)g * 16 * 257; dst_stride = 257; raw = false;
  } else if (b < 246) {
    const int r = b - 214, g = r >> 1, tile = r & 1;
    Wa = W3a; ba = b3a; Wb = W3b; bb = b3b;
    outn = 321; colbase = tile * 256; jcount = 100;
    k0 = 48 + g * 16; kn = 16;
    dst = out + 90160 + (size_t)g * 16 * 321; dst_stride = 321; raw = false;
  } else {
    const int tile = b - 246;
    Wa = W4a; ba = b4a; Wb = W4b; bb = b4b;
    outn = 1542; colbase = tile * 256; jcount = 100;
    k0 = 304; kn = 3;
    dst = out + 172336; dst_stride = 1542; raw = false;
  }

  // --- preamble: sS[k0..k0+kn) from psum partials ---
  {
    const int kl = t >> 4, pc = t & 15;
    float s = 0.f;
    if (kl < kn) {
      const int kk = k0 + kl;
#pragma unroll 4
      for (int i = pc; i < RS_BLOCKS; i += 16) s += psum[(size_t)i * PS_STRIDE + kk];
    }
    pred[kl][pc] = s;
    __syncthreads();
    if (t < 16) {
      float sum = 0.f;
#pragma unroll
      for (int i = 0; i < 16; ++i) sum += pred[t][i];
      sHs[t] = (t < kn) ? fmaxf(sum + bd2[15 * (k0 + t) + 1], 0.f) : 0.f;
    }
    __syncthreads();
  }

  for (int e = t; e < jcount * 16; e += 256) {
    const int j = e >> 4, k = e & 15;
    float hv = 0.f;
    if (k < kn) hv = fmaxf(fmaf(sHs[k], Wa[jbase + j], ba[jbase + j]), 0.f);
    sH[e] = hv;  // layout: sH[j*16 + k]
  }
  __syncthreads();

  const int m = colbase + t;
  if (m < outn) {
    float acc[16];
#pragma unroll
    for (int k = 0; k < 16; ++k) acc[k] = 0.f;
    const float* wb = Wb + (size_t)jbase * outn + m;
    // depth-2 pipelined: both weight loads issue before the FMA chains.
    for (int j = 0; j < jcount; j += 2) {
      const float w0 = wb[(size_t)j * outn];            // coalesced across lanes
      const float w1 = wb[(size_t)(j + 1) * outn];
      const float4* hp0 = (const float4*)(sH + j * 16); // broadcast reads
      const float4 a0 = hp0[0], a1 = hp0[1], a2 = hp0[2], a3 = hp0[3];
      acc[0]  = fmaf(a0.x, w0, acc[0]);   acc[1]  = fmaf(a0.y, w0, acc[1]);
      acc[2]  = fmaf(a0.z, w0, acc[2]);   acc[3]  = fmaf(a0.w, w0, acc[3]);
      acc[4]  = fmaf(a1.x, w0, acc[4]);   acc[5]  = fmaf(a1.y, w0, acc[5]);
      acc[6]  = fmaf(a1.z, w0, acc[6]);   acc[7]  = fmaf(a1.w, w0, acc[7]);
      acc[8]  = fmaf(a2.x, w0, acc[8]);   acc[9]  = fmaf(a2.y, w0, acc[9]);
      acc[10] = fmaf(a2.z, w0, acc[10]);  acc[11] = fmaf(a2.w, w0, acc[11]);
      acc[12] = fmaf(a3.x, w0, acc[12]);  acc[13] = fmaf(a3.y, w0, acc[13]);
      acc[14] = fmaf(a3.z, w0, acc[14]);  acc[15] = fmaf(a3.w, w0, acc[15]);
      const float4* hp1 = (const float4*)(sH + (j + 1) * 16);
      const float4 c0 = hp1[0], c1 = hp1[1], c2 = hp1[2], c3 = hp1[3];
      acc[0]  = fmaf(c0.x, w1, acc[0]);   acc[1]  = fmaf(c0.y, w1, acc[1]);
      acc[2]  = fmaf(c0.z, w1, acc[2]);   acc[3]  = fmaf(c0.w, w1, acc[3]);
      acc[4]  = fmaf(c1.x, w1, acc[4]);   acc[5]  = fmaf(c1.y, w1, acc[5]);
      acc[6]  = fmaf(c1.z, w1, acc[6]);   acc[7]  = fmaf(c1.w, w1, acc[7]);
      acc[8]  = fmaf(c2.x, w1, acc[8]);   acc[9]  = fmaf(c2.y, w1, acc[9]);
      acc[10] = fmaf(c2.z, w1, acc[10]);  acc[11] = fmaf(c2.w, w1, acc[11]);
      acc[12] = fmaf(c3.x, w1, acc[12]);  acc[13] = fmaf(c3.y, w1, acc[13]);
      acc[14] = fmaf(c3.z, w1, acc[14]);  acc[15] = fmaf(c3.w, w1, acc[15]);
    }
    if (raw) {
#pragma unroll
      for (int k = 0; k < 16; ++k) dst[(size_t)k * dst_stride + m] = acc[k];
    } else {
      const float bv = bb[m];
      for (int k = 0; k < kn; ++k)
        dst[(size_t)k * dst_stride + m] = fmaxf(acc[k] + bv, 0.f);
    }
  }
}

// K4: seg1 finalize: sum 10 j-chunk partials + bias, relu -> out[0..81936).
__global__ __launch_bounds__(256) void k_final_seg1(
    const float* __restrict__ ws3, const float* __restrict__ b1b, float* __restrict__ out) {
  const int i = blockIdx.x * 256 + threadIdx.x;
  if (i >= 16 * 5121) return;
  const int k = i / 5121;
  const int m = i - k * 5121;
  float s = b1b[m];
#pragma unroll
  for (int c = 0; c < SEG1_JC; ++c) s += ws3[((size_t)c * 16 + k) * 5121 + m];
  out[i] = fmaxf(s, 0.f);
}

extern "C" void kernel_launch(void* const* d_in, const int* in_sizes, int n_in,
                              void* d_out, int out_size, void* d_ws, size_t ws_size,
                              hipStream_t stream) {
  const float* x   = (const float*)d_in[0];
  const float* Wd1 = (const float*)d_in[1];
  const float* bd1 = (const float*)d_in[2];
  const float* Wd2 = (const float*)d_in[3];
  const float* bd2 = (const float*)d_in[4];
  const float* W1a = (const float*)d_in[5];
  const float* b1a = (const float*)d_in[6];
  const float* W1b = (const float*)d_in[7];
  const float* b1b = (const float*)d_in[8];
  const float* W2a = (const float*)d_in[9];
  const float* b2a = (const float*)d_in[10];
  const float* W2b = (const float*)d_in[11];
  const float* b2b = (const float*)d_in[12];
  const float* W3a = (const float*)d_in[13];
  const float* b3a = (const float*)d_in[14];
  const float* W3b = (const float*)d_in[15];
  const float* b3b = (const float*)d_in[16];
  const float* W4a = (const float*)d_in[17];
  const float* b4a = (const float*)d_in[18];
  const float* W4b = (const float*)d_in[19];
  const float* b4b = (const float*)d_in[20];
  float* out = (float*)d_out;

  float* ws   = (float*)d_ws;
  float* ws1  = ws;                              // ws1_T: 1000 * 512 floats
  float* psum = ws1 + (size_t)N1 * G1_CHUNKS;    // 250 * 320
  float* ws3  = psum + (size_t)RS_BLOCKS * PS_STRIDE;  // 10 * 16 * 5121

  hipLaunchKernelGGL(k_gemv1_partial, dim3(G1_CHUNKS), dim3(256), 0, stream, x, Wd1, ws1);
  hipLaunchKernelGGL(k_reduce_scalars, dim3(RS_BLOCKS), dim3(256), 0, stream,
                     ws1, bd1, Wd2, psum);
  hipLaunchKernelGGL(k_segments, dim3(253), dim3(256), 0, stream,
                     psum, bd2, W1a, b1a, W1b, W2a, b2a, W2b, b2b,
                     W3a, b3a, W3b, b3b, W4a, b4a, W4b, b4b, ws3, out);
  hipLaunchKernelGGL(k_final_seg1, dim3((16 * 5121 + 255) / 256), dim3(256), 0, stream,
                     ws3, b1b, out);
}